// Round 15
// baseline (601.214 us; speedup 1.0000x reference)
//
#include <hip/hip_runtime.h>
#include <hip/hip_bf16.h>
#include <stdint.h>

#define DIM 3072
#define SEQ 4096
#define NH 24
#define HD 128

typedef __hip_bfloat16 bf16;
typedef __bf16 bfv8 __attribute__((ext_vector_type(8)));
typedef float f32x4 __attribute__((ext_vector_type(4)));
typedef float f32x16 __attribute__((ext_vector_type(16)));
typedef unsigned short us4 __attribute__((ext_vector_type(4)));
typedef unsigned short us8 __attribute__((ext_vector_type(8)));

template <int N> struct ic { static constexpr int value = N; };

__device__ __forceinline__ void async16(void* lds, const void* g) {
  __builtin_amdgcn_global_load_lds((const __attribute__((address_space(1))) void*)g,
                                   (__attribute__((address_space(3))) void*)lds, 16, 0, 0);
}

__device__ __forceinline__ unsigned short f2bf(float f) {
  unsigned int u = __builtin_bit_cast(unsigned int, f);
  u += 0x7fffu + ((u >> 16) & 1u);
  return (unsigned short)(u >> 16);
}
__device__ __forceinline__ float bf2f(unsigned short b) {
  return __builtin_bit_cast(float, (unsigned int)b << 16);
}
__device__ __forceinline__ unsigned int cvtpk(float lo, float hi) {
  unsigned int r;
  asm("v_cvt_pk_bf16_f32 %0, %1, %2" : "=v"(r) : "v"(lo), "v"(hi));
  return r;
}
__device__ __forceinline__ void pl32swap(unsigned int& a, unsigned int& b) {
  asm volatile("v_permlane32_swap_b32 %0, %1" : "+v"(a), "+v"(b));
}
#if __has_builtin(__builtin_amdgcn_exp2f)
__device__ __forceinline__ float fexp2(float x) { return __builtin_amdgcn_exp2f(x); }
#else
__device__ __forceinline__ float fexp2(float x) { return exp2f(x); }
#endif

#define MFMA16(a, b, c) __builtin_amdgcn_mfma_f32_16x16x32_bf16((a), (b), (c), 0, 0, 0)
#define MFMA32(a, b, c) __builtin_amdgcn_mfma_f32_32x32x16_bf16((a), (b), (c), 0, 0, 0)

// ---------------- kernel 1: fp32 -> bf16 cast (hidden states) ----------------
__global__ __launch_bounds__(256) void k_cast(const float4* __restrict__ in,
                                              us4* __restrict__ o, int n4) {
  int i = blockIdx.x * 256 + threadIdx.x;
  if (i >= n4) return;
  float4 v = in[i];
  us4 r;
  r.x = f2bf(v.x); r.y = f2bf(v.y); r.z = f2bf(v.z); r.w = f2bf(v.w);
  o[i] = r;
}

// ------------- kernel 2: transpose-cast W (KxN fp32) -> WT (NxK bf16) -------------
__global__ __launch_bounds__(256) void k_transW(const float* __restrict__ W0,
    const float* __restrict__ W1, const float* __restrict__ W2,
    unsigned short* __restrict__ T0, unsigned short* __restrict__ T1,
    unsigned short* __restrict__ T2) {
  int z = blockIdx.z;
  const float* W = (z == 0) ? W0 : (z == 1) ? W1 : W2;
  unsigned short* T = (z == 0) ? T0 : (z == 1) ? T1 : T2;
  int kb = blockIdx.y * 64;
  int nb = blockIdx.x * 64;
  __shared__ float tile[64 * 64];
  int t = threadIdx.x;
#pragma unroll
  for (int p = 0; p < 4; ++p) {
    int cid = p * 256 + t;
    int row = cid >> 4, c4 = cid & 15;
    int slot = (c4 + (row >> 3)) & 15;
    float4 v = *(const float4*)&W[(size_t)(kb + row) * DIM + nb + c4 * 4];
    *(float4*)&tile[row * 64 + slot * 4] = v;
  }
  __syncthreads();
#pragma unroll
  for (int p = 0; p < 2; ++p) {
    int cid = p * 256 + t;
    int nl = cid >> 3, c8 = cid & 7;
    us8 o;
#pragma unroll
    for (int j = 0; j < 8; ++j) {
      int k = c8 * 8 + j;
      int slot = ((nl >> 2) + (k >> 3)) & 15;
      o[j] = f2bf(tile[k * 64 + slot * 4 + (nl & 3)]);
    }
    *(us8*)&T[(size_t)(nb + nl) * DIM + kb + c8 * 8] = o;
  }
}

// ------------- kernel 3: GEMM, 8-phase counted-vmcnt, BM=128 BN=384 BK=64 ----
// R15: same schedule as R14 but geometry re-fit to the problem: grid 8x32x3 =
// 768 blocks = EXACTLY 3 rounds at 1 block/CU (R14's 576 ran as 3 rounds with a
// 25%-occupied tail). 8 waves 2Mx4N -> per-wave 64x96 (acc 96 regs, no spill).
// A-half = 1 gload_lds/thread, B-half = 3. Swizzle c4 ^ ((row>>1)&3) both-sides.
__global__ __launch_bounds__(512, 2) void k_gemm(const unsigned short* __restrict__ A,
    const unsigned short* __restrict__ B0, const unsigned short* __restrict__ B1,
    const unsigned short* __restrict__ B2, const float* __restrict__ c0,
    const float* __restrict__ c1, const float* __restrict__ c2,
    unsigned short* __restrict__ o0, unsigned short* __restrict__ o1,
    unsigned short* __restrict__ o2) {
  const int z = blockIdx.z;
  const unsigned short* Bt = (z == 0) ? B0 : (z == 1) ? B1 : B2;
  const float* bias = (z == 0) ? c0 : (z == 1) ? c1 : c2;
  unsigned short* outp = (z == 0) ? o0 : (z == 1) ? o1 : o2;
  const int nb = blockIdx.x * 384;
  const int mb = blockIdx.y * 128;
  const int tid = threadIdx.x;
  const int w = tid >> 6, l = tid & 63;
  const int wm = w >> 2, wn = w & 3;   // 2M x 4N; wave owns 64(M) x 96(N)
  const int lq = l & 15, lg = l >> 4;

  __shared__ unsigned short lA[2 * 2 * 4096];   // [buf][kh][128][32]  32 KB
  __shared__ unsigned short lB[2 * 2 * 12288];  // [buf][kh][384][32]  96 KB

  // ---- fragment read offsets (shorts) ----
  int aoff[4], boff[6];
#pragma unroll
  for (int mf = 0; mf < 4; ++mf) {
    int rA = wm * 64 + mf * 16 + lq;
    aoff[mf] = rA * 32 + ((lg ^ ((rA >> 1) & 3)) * 8);
  }
#pragma unroll
  for (int nf = 0; nf < 6; ++nf) {
    int rB = wn * 96 + nf * 16 + lq;
    boff[nf] = rB * 32 + ((lg ^ ((rB >> 1) & 3)) * 8);
  }

  // ---- staging pointers ----
  const int rowA = tid >> 2;
  const unsigned short* apK0 =
      A + (size_t)(mb + rowA) * DIM + (((tid & 3) ^ ((rowA >> 1) & 3)) * 8);
  const unsigned short* apK1 = apK0 + 32;
  const int dstA = w * 512;
  const unsigned short *bpK0[3], *bpK1[3];
  int dstB[3];
#pragma unroll
  for (int j = 0; j < 3; ++j) {
    int rowB = (w * 3 + j) * 16 + (l >> 2);
    bpK0[j] = Bt + (size_t)(nb + rowB) * DIM + (((l & 3) ^ ((rowB >> 1) & 3)) * 8);
    bpK1[j] = bpK0[j] + 32;
    dstB[j] = (w * 3 + j) * 512;
  }

#define SA0(B) do { async16(&lA[(B) * 8192 + dstA], apK0); apK0 += 64; } while (0)
#define SA1(B) do { async16(&lA[(B) * 8192 + 4096 + dstA], apK1); apK1 += 64; } while (0)
#define SB0(B)                                                                 \
  do {                                                                         \
    async16(&lB[(B) * 24576 + dstB[0]], bpK0[0]); bpK0[0] += 64;               \
    async16(&lB[(B) * 24576 + dstB[1]], bpK0[1]); bpK0[1] += 64;               \
    async16(&lB[(B) * 24576 + dstB[2]], bpK0[2]); bpK0[2] += 64;               \
  } while (0)
#define SB1(B)                                                                 \
  do {                                                                         \
    async16(&lB[(B) * 24576 + 12288 + dstB[0]], bpK1[0]); bpK1[0] += 64;       \
    async16(&lB[(B) * 24576 + 12288 + dstB[1]], bpK1[1]); bpK1[1] += 64;       \
    async16(&lB[(B) * 24576 + 12288 + dstB[2]], bpK1[2]); bpK1[2] += 64;       \
  } while (0)

  f32x4 acc[4][6];
#pragma unroll
  for (int i = 0; i < 4; ++i)
#pragma unroll
    for (int j = 0; j < 6; ++j) acc[i][j] = (f32x4){0.f, 0.f, 0.f, 0.f};

  // prologue: t0 complete + Kh0(t1); vmcnt(4) -> t0 resident, Kh0(t1) in flight
  SA0(0); SB0(0); SA1(0); SB1(0); SA0(1); SB0(1);
  asm volatile("s_waitcnt vmcnt(4)" ::: "memory");
  __builtin_amdgcn_s_barrier();
  __builtin_amdgcn_sched_barrier(0);

  auto tileG = [&](auto bufc, auto kh1c, auto kh0c, auto waitc) {
    constexpr int C = decltype(bufc)::value;
    constexpr int DO1 = decltype(kh1c)::value;   // stage Kh1(t+1) -> buf C^1
    constexpr int DO0 = decltype(kh0c)::value;   // stage Kh0(t+2) -> buf C
    constexpr int WN = decltype(waitc)::value;
    bfv8 aF[2], bF[6];
    // ---- p0: kh0, mf0-1 x nf0-5 ----
#pragma unroll
    for (int nf = 0; nf < 6; ++nf)
      bF[nf] = *(const bfv8*)&lB[C * 24576 + boff[nf]];
    aF[0] = *(const bfv8*)&lA[C * 8192 + aoff[0]];
    aF[1] = *(const bfv8*)&lA[C * 8192 + aoff[1]];
    if constexpr (DO1) SA1(C ^ 1);
    __builtin_amdgcn_s_barrier();
    __builtin_amdgcn_sched_barrier(0);
    __builtin_amdgcn_s_setprio(1);
#pragma unroll
    for (int mf = 0; mf < 2; ++mf)
#pragma unroll
      for (int nf = 0; nf < 6; ++nf) acc[mf][nf] = MFMA16(aF[mf], bF[nf], acc[mf][nf]);
    __builtin_amdgcn_s_setprio(0);
    __builtin_amdgcn_s_barrier();
    // ---- p1: kh0, mf2-3 ----
    aF[0] = *(const bfv8*)&lA[C * 8192 + aoff[2]];
    aF[1] = *(const bfv8*)&lA[C * 8192 + aoff[3]];
    if constexpr (DO1) SB1(C ^ 1);
    __builtin_amdgcn_s_barrier();
    __builtin_amdgcn_sched_barrier(0);
    __builtin_amdgcn_s_setprio(1);
#pragma unroll
    for (int mf = 0; mf < 2; ++mf)
#pragma unroll
      for (int nf = 0; nf < 6; ++nf)
        acc[mf + 2][nf] = MFMA16(aF[mf], bF[nf], acc[mf + 2][nf]);
    __builtin_amdgcn_s_setprio(0);
    __builtin_amdgcn_s_barrier();
    // ---- p2: kh1, mf0-1 ----
#pragma unroll
    for (int nf = 0; nf < 6; ++nf)
      bF[nf] = *(const bfv8*)&lB[C * 24576 + 12288 + boff[nf]];
    aF[0] = *(const bfv8*)&lA[C * 8192 + 4096 + aoff[0]];
    aF[1] = *(const bfv8*)&lA[C * 8192 + 4096 + aoff[1]];
    if constexpr (DO0) SA0(C);
    __builtin_amdgcn_s_barrier();
    __builtin_amdgcn_sched_barrier(0);
    __builtin_amdgcn_s_setprio(1);
#pragma unroll
    for (int mf = 0; mf < 2; ++mf)
#pragma unroll
      for (int nf = 0; nf < 6; ++nf) acc[mf][nf] = MFMA16(aF[mf], bF[nf], acc[mf][nf]);
    __builtin_amdgcn_s_setprio(0);
    __builtin_amdgcn_s_barrier();
    // ---- p3: kh1, mf2-3 ----
    aF[0] = *(const bfv8*)&lA[C * 8192 + 4096 + aoff[2]];
    aF[1] = *(const bfv8*)&lA[C * 8192 + 4096 + aoff[3]];
    if constexpr (DO0) SB0(C);
    __builtin_amdgcn_s_barrier();
    __builtin_amdgcn_sched_barrier(0);
    __builtin_amdgcn_s_setprio(1);
#pragma unroll
    for (int mf = 0; mf < 2; ++mf)
#pragma unroll
      for (int nf = 0; nf < 6; ++nf)
        acc[mf + 2][nf] = MFMA16(aF[mf], bF[nf], acc[mf + 2][nf]);
    __builtin_amdgcn_s_setprio(0);
    if constexpr (WN == 4)
      asm volatile("s_waitcnt vmcnt(4)" ::: "memory");
    else if constexpr (WN == 0)
      asm volatile("s_waitcnt vmcnt(0)" ::: "memory");
    __builtin_amdgcn_s_barrier();
    __builtin_amdgcn_sched_barrier(0);
  };

  // K-tiles t = 0..47. Main t=0..45; tails t=46 (drain), t=47 (no stage).
  for (int it = 0; it < 23; ++it) {
    tileG(ic<0>{}, ic<1>{}, ic<1>{}, ic<4>{});
    tileG(ic<1>{}, ic<1>{}, ic<1>{}, ic<4>{});
  }
  tileG(ic<0>{}, ic<1>{}, ic<0>{}, ic<0>{});
  tileG(ic<1>{}, ic<0>{}, ic<0>{}, ic<-1>{});

  // ---- epilogue: + bias, bf16 head-major ----
#pragma unroll
  for (int nf = 0; nf < 6; ++nf) {
    int n = nb + wn * 96 + nf * 16 + lq;
    float bv_ = bias[n];
    int hh = n >> 7, dd = n & 127;
    unsigned short* obase = outp + (size_t)hh * SEQ * HD + dd;
#pragma unroll
    for (int mf = 0; mf < 4; ++mf) {
      int srow = mb + wm * 64 + mf * 16 + lg * 4;
#pragma unroll
      for (int r = 0; r < 4; ++r)
        obase[(size_t)(srow + r) * HD] = f2bf(acc[mf][nf][r] + bv_);
    }
  }
#undef SA0
#undef SA1
#undef SB0
#undef SB1
}

// ------------- kernel 4: per-(h,s)-row RMSNorm + RoPE (in place, bf16) -------------
__global__ __launch_bounds__(256) void k_rmsrope(unsigned short* __restrict__ qb,
    unsigned short* __restrict__ kbuf, const float* __restrict__ cosT,
    const float* __restrict__ sinT, const float* __restrict__ gq,
    const float* __restrict__ gk) {
  int rowid = blockIdx.x * 4 + (threadIdx.x >> 6);
  int l = threadIdx.x & 63;
  int which = (rowid >= NH * SEQ) ? 1 : 0;
  int r2 = which ? rowid - NH * SEQ : rowid;
  int hh = r2 >> 12;
  int s = r2 & 4095;
  unsigned short* base = (which ? kbuf : qb) + ((size_t)hh * SEQ + s) * HD + 2 * l;
  const float* g = which ? gk : gq;
  unsigned int u = *(const unsigned int*)base;
  float x0 = bf2f((unsigned short)(u & 0xffffu));
  float x1 = bf2f((unsigned short)(u >> 16));
  float ss = x0 * x0 + x1 * x1;
#pragma unroll
  for (int o = 1; o < 64; o <<= 1) ss += __shfl_xor(ss, o);
  float rr = rsqrtf(ss * (1.0f / 128.0f) + 1e-6f);
  int d0 = 2 * l;
  float c0v = cosT[s * HD + d0], c1v = cosT[s * HD + d0 + 1];
  float s0v = sinT[s * HD + d0], s1v = sinT[s * HD + d0 + 1];
  float y0 = x0 * rr * g[d0];
  float y1 = x1 * rr * g[d0 + 1];
  float o0 = y0 * c0v - y1 * s0v;
  float o1 = y1 * c1v + y0 * s1v;
  if (!which) { o0 *= 0.1275174373f; o1 *= 0.1275174373f; } // log2(e)/sqrt(128)
  *(unsigned int*)base = (unsigned int)f2bf(o0) | ((unsigned int)f2bf(o1) << 16);
}

// ------------- kernel 5: V transpose  v[h][s][d] -> vt[h][d][s] -------------
__global__ __launch_bounds__(256) void k_transV(const unsigned short* __restrict__ vb,
                                                unsigned short* __restrict__ vt) {
  int hh = blockIdx.y;
  int sb = blockIdx.x * 64;
  __shared__ unsigned short tile[64 * 128];
  int t = threadIdx.x;
#pragma unroll
  for (int p = 0; p < 4; ++p) {
    int cid = p * 256 + t;
    int row = cid >> 4, c = cid & 15;
    int slot = (c + (row >> 3)) & 15;
    us8 v = *(const us8*)&vb[((size_t)hh * SEQ + sb + row) * HD + c * 8];
    *(us8*)&tile[row * 128 + slot * 8] = v;
  }
  __syncthreads();
#pragma unroll
  for (int p = 0; p < 4; ++p) {
    int cid = p * 256 + t;
    int d = cid >> 3, c8 = cid & 7;
    us8 o;
#pragma unroll
    for (int j = 0; j < 8; ++j) {
      int s = c8 * 8 + j;
      int slot = ((d >> 3) + (s >> 3)) & 15;
      o[j] = tile[s * 128 + slot * 8 + (d & 7)];
    }
    *(us8*)&vt[((size_t)hh * HD + d) * SEQ + sb + c8 * 8] = o;
  }
}

// ------------- kernel 6: flash attention (R13: head-congruent XCD clustering) -------------
__global__ __launch_bounds__(256, 2) void k_attn(const unsigned short* __restrict__ qg,
    const unsigned short* __restrict__ kg, const unsigned short* __restrict__ vtg,
    float* __restrict__ outp) {
  const int bflat = blockIdx.x;
  const int h = bflat % 24;
  const int qb0 = (bflat / 24) * 128;
  const int t = threadIdx.x;
  const int w = t >> 6, l = t & 63;
  const int l31 = l & 31, hi = l >> 5;

  __shared__ unsigned short lKf[2 * 8192];
  __shared__ unsigned short lVf[2 * 8192];

  bfv8 qf[8];
  {
    const unsigned short* qrow = qg + ((size_t)h * SEQ + qb0 + w * 32 + l31) * HD + hi * 8;
#pragma unroll
    for (int ks = 0; ks < 8; ++ks) qf[ks] = *(const bfv8*)(qrow + ks * 16);
  }

  int kidx[8], vidx[4][2];
#pragma unroll
  for (int ks = 0; ks < 8; ++ks)
    kidx[ks] = l31 * 128 + (((ks * 2 + hi) ^ (l31 & 7) ^ ((l31 >> 3) & 1)) * 8);
#pragma unroll
  for (int dt = 0; dt < 4; ++dt)
#pragma unroll
    for (int ksub = 0; ksub < 2; ++ksub)
      vidx[dt][ksub] =
          (dt * 32 + l31) * 32 + (((ksub * 2 + hi) ^ (l31 & 3) ^ ((l31 >> 2) & 3)) * 8);

  const unsigned short *kp0, *kp1, *vp0, *vp1;
  {
    int kr0 = w * 4 + (l >> 4), kr1 = 16 + kr0;
    kp0 = kg + ((size_t)h * SEQ + kr0) * HD + (((l & 15) ^ (kr0 & 7) ^ ((kr0 >> 3) & 1)) * 8);
    kp1 = kg + ((size_t)h * SEQ + kr1) * HD + (((l & 15) ^ (kr1 & 7) ^ ((kr1 >> 3) & 1)) * 8);
    int vr0 = w * 16 + (l >> 2), vr1 = 64 + vr0;
    vp0 = vtg + ((size_t)h * HD + vr0) * SEQ + (((l & 3) ^ (vr0 & 3) ^ ((vr0 >> 2) & 3)) * 8);
    vp1 = vtg + ((size_t)h * HD + vr1) * SEQ + (((l & 3) ^ (vr1 & 3) ^ ((vr1 >> 2) & 3)) * 8);
  }

#define STAGE(B)                                                              \
  do {                                                                        \
    async16(&lKf[(B) * 8192 + w * 512], kp0);                                 \
    async16(&lKf[(B) * 8192 + 2048 + w * 512], kp1);                          \
    async16(&lKf[(B) * 8192 + 4096 + w * 512], kp0 + 32 * HD);                \
    async16(&lKf[(B) * 8192 + 6144 + w * 512], kp1 + 32 * HD);                \
    async16(&lVf[(B) * 8192 + w * 512], vp0);                                 \
    async16(&lVf[(B) * 8192 + 2048 + w * 512], vp1);                          \
    async16(&lVf[(B) * 8192 + 4096 + w * 512], vp0 + 32);                     \
    async16(&lVf[(B) * 8192 + 6144 + w * 512], vp1 + 32);                     \
    kp0 += 64 * HD; kp1 += 64 * HD; vp0 += 64; vp1 += 64;                     \
  } while (0)

  f32x16 oacc[4];
#pragma unroll
  for (int dt = 0; dt < 4; ++dt)
#pragma unroll
    for (int r = 0; r < 16; ++r) oacc[dt][r] = 0.f;
  float l_run = 0.f;

  STAGE(0);

  auto phase = [&](auto bufc, auto stagec) {
    constexpr int CUR = decltype(bufc)::value;
    constexpr int DOSTAGE = decltype(stagec)::value;
    asm volatile("s_waitcnt vmcnt(0)" ::: "memory");
    __builtin_amdgcn_s_barrier();
    __builtin_amdgcn_sched_barrier(0);
    if constexpr (DOSTAGE) STAGE(CUR ^ 1);
    __builtin_amdgcn_sched_barrier(0);

    f32x16 sa, sb;
#pragma unroll
    for (int r = 0; r < 16; ++r) { sa[r] = 0.f; sb[r] = 0.f; }
    __builtin_amdgcn_s_setprio(1);
#pragma unroll
    for (int ks = 0; ks < 8; ++ks) {
      bfv8 kfa = *(const bfv8*)&lKf[CUR * 8192 + kidx[ks]];
      bfv8 kfb = *(const bfv8*)&lKf[CUR * 8192 + 4096 + kidx[ks]];
      sa = MFMA32(kfa, qf[ks], sa);
      sb = MFMA32(kfb, qf[ks], sb);
    }
    __builtin_amdgcn_s_setprio(0);

#pragma unroll
    for (int r = 0; r < 16; ++r) { sa[r] = fexp2(sa[r]); sb[r] = fexp2(sb[r]); }
    {
      float a0 = (sa[0] + sa[1]) + (sa[2] + sa[3]);
      float a1 = (sa[4] + sa[5]) + (sa[6] + sa[7]);
      float a2 = (sa[8] + sa[9]) + (sa[10] + sa[11]);
      float a3 = (sa[12] + sa[13]) + (sa[14] + sa[15]);
      float b0 = (sb[0] + sb[1]) + (sb[2] + sb[3]);
      float b1 = (sb[4] + sb[5]) + (sb[6] + sb[7]);
      float b2 = (sb[8] + sb[9]) + (sb[10] + sb[11]);
      float b3 = (sb[12] + sb[13]) + (sb[14] + sb[15]);
      l_run += ((a0 + a1) + (a2 + a3)) + ((b0 + b1) + (b2 + b3));
    }

    bfv8 paA[2], paB[2];
    {
      unsigned int a0 = cvtpk(sa[0], sa[1]), a1 = cvtpk(sa[2], sa[3]);
      unsigned int b0 = cvtpk(sa[4], sa[5]), b1 = cvtpk(sa[6], sa[7]);
      unsigned int c0 = cvtpk(sa[8], sa[9]), c1 = cvtpk(sa[10], sa[11]);
      unsigned int d0 = cvtpk(sa[12], sa[13]), d1 = cvtpk(sa[14], sa[15]);
      pl32swap(a0, b0); pl32swap(a1, b1); pl32swap(c0, d0); pl32swap(c1, d1);
      paA[0] = __builtin_bit_cast(bfv8, make_uint4(a0, a1, b0, b1));
      paA[1] = __builtin_bit_cast(bfv8, make_uint4(c0, c1, d0, d1));
      a0 = cvtpk(sb[0], sb[1]); a1 = cvtpk(sb[2], sb[3]);
      b0 = cvtpk(sb[4], sb[5]); b1 = cvtpk(sb[6], sb[7]);
      c0 = cvtpk(sb[8], sb[9]); c1 = cvtpk(sb[10], sb[11]);
      d0 = cvtpk(sb[12], sb[13]); d1 = cvtpk(sb[14], sb[15]);
      pl32swap(a0, b0); pl32swap(a1, b1); pl32swap(c0, d0); pl32swap(c1, d1);
      paB[0] = __builtin_bit_cast(bfv8, make_uint4(a0, a1, b0, b1));
      paB[1] = __builtin_bit_cast(bfv8, make_uint4(c0, c1, d0, d1));
    }

    __builtin_amdgcn_s_setprio(1);
#pragma unroll
    for (int dt = 0; dt < 4; ++dt) {
#pragma unroll
      for (int ksub = 0; ksub < 2; ++ksub) {
        bfv8 vfa = *(const bfv8*)&lVf[CUR * 8192 + vidx[dt][ksub]];
        oacc[dt] = MFMA32(paA[ksub], vfa, oacc[dt]);
      }
#pragma unroll
      for (int ksub = 0; ksub < 2; ++ksub) {
        bfv8 vfb = *(const bfv8*)&lVf[CUR * 8192 + 4096 + vidx[dt][ksub]];
        oacc[dt] = MFMA32(paB[ksub], vfb, oacc[dt]);
      }
    }
    __builtin_amdgcn_s_setprio(0);
  };

  for (int it = 0; it < 31; ++it) {
    phase(ic<0>{}, ic<1>{});
    phase(ic<1>{}, ic<1>{});
  }
  phase(ic<0>{}, ic<1>{});
  phase(ic<1>{}, ic<0>{});

  l_run += __shfl_xor(l_run, 32);
  float linv = 1.0f / l_run;
#pragma unroll
  for (int r = 0; r < 16; ++r) {
    int qr = (r & 3) + 8 * (r >> 2) + 4 * hi;
    float lr = __shfl(linv, qr);
    float* orow = outp + (size_t)(qb0 + w * 32 + qr) * DIM + h * HD;
#pragma unroll
    for (int dt = 0; dt < 4; ++dt) orow[dt * 32 + l31] = oacc[dt][r] * lr;
  }
#undef STAGE
}

extern "C" void kernel_launch(void* const* d_in, const int* in_sizes, int n_in,
                              void* d_out, int out_size, void* d_ws, size_t ws_size,
                              hipStream_t stream) {
  const float* hs = (const float*)d_in[0];
  const float* cosT = (const float*)d_in[1];
  const float* sinT = (const float*)d_in[2];
  const float* Wq = (const float*)d_in[3];
  const float* bq = (const float*)d_in[4];
  const float* Wk = (const float*)d_in[5];
  const float* bk = (const float*)d_in[6];
  const float* Wv = (const float*)d_in[7];
  const float* bv = (const float*)d_in[8];
  const float* gq = (const float*)d_in[9];
  const float* gk = (const float*)d_in[10];
  float* out = (float*)d_out;

  char* ws = (char*)d_ws;
  const size_t SZ_HS = (size_t)SEQ * DIM * 2;
  const size_t SZ_W = (size_t)DIM * DIM * 2;
  const size_t SZ_HEAD = (size_t)NH * SEQ * HD * 2;
  unsigned short* hsb = (unsigned short*)ws;               ws += SZ_HS;
  unsigned short* WqT = (unsigned short*)ws;               ws += SZ_W;
  unsigned short* WkT = (unsigned short*)ws;               ws += SZ_W;
  unsigned short* WvT = (unsigned short*)ws;               ws += SZ_W;
  unsigned short* q_b = (unsigned short*)ws;               ws += SZ_HEAD;
  unsigned short* k_b = (unsigned short*)ws;               ws += SZ_HEAD;
  unsigned short* v_b = (unsigned short*)ws;               ws += SZ_HEAD;
  unsigned short* vtr = (unsigned short*)ws;               ws += SZ_HEAD;

  int n4 = SEQ * DIM / 4;
  k_cast<<<dim3(n4 / 256), dim3(256), 0, stream>>>((const float4*)hs, (us4*)hsb, n4);
  k_transW<<<dim3(48, 48, 3), dim3(256), 0, stream>>>(Wq, Wk, Wv, WqT, WkT, WvT);
  k_gemm<<<dim3(8, 32, 3), dim3(512), 0, stream>>>(hsb, WqT, WkT, WvT, bq, bk, bv,
                                                   q_b, k_b, v_b);
  k_rmsrope<<<dim3(2 * NH * SEQ / 4), dim3(256), 0, stream>>>(q_b, k_b, cosT, sinT, gq, gk);
  k_transV<<<dim3(64, 24), dim3(256), 0, stream>>>(v_b, vtr);
  k_attn<<<dim3(768), dim3(256), 0, stream>>>(q_b, k_b, vtr, out);
}

// Round 16
// 517.190 us; speedup vs baseline: 1.1625x; 1.1625x over previous
//
#include <hip/hip_runtime.h>
#include <hip/hip_bf16.h>
#include <stdint.h>

#define DIM 3072
#define SEQ 4096
#define NH 24
#define HD 128

typedef __hip_bfloat16 bf16;
typedef __bf16 bfv8 __attribute__((ext_vector_type(8)));
typedef float f32x4 __attribute__((ext_vector_type(4)));
typedef float f32x16 __attribute__((ext_vector_type(16)));
typedef unsigned short us4 __attribute__((ext_vector_type(4)));
typedef unsigned short us8 __attribute__((ext_vector_type(8)));

template <int N> struct ic { static constexpr int value = N; };

__device__ __forceinline__ void async16(void* lds, const void* g) {
  __builtin_amdgcn_global_load_lds((const __attribute__((address_space(1))) void*)g,
                                   (__attribute__((address_space(3))) void*)lds, 16, 0, 0);
}

__device__ __forceinline__ unsigned short f2bf(float f) {
  unsigned int u = __builtin_bit_cast(unsigned int, f);
  u += 0x7fffu + ((u >> 16) & 1u);
  return (unsigned short)(u >> 16);
}
__device__ __forceinline__ float bf2f(unsigned short b) {
  return __builtin_bit_cast(float, (unsigned int)b << 16);
}
__device__ __forceinline__ unsigned int cvtpk(float lo, float hi) {
  unsigned int r;
  asm("v_cvt_pk_bf16_f32 %0, %1, %2" : "=v"(r) : "v"(lo), "v"(hi));
  return r;
}
__device__ __forceinline__ void pl32swap(unsigned int& a, unsigned int& b) {
  asm volatile("v_permlane32_swap_b32 %0, %1" : "+v"(a), "+v"(b));
}
#if __has_builtin(__builtin_amdgcn_exp2f)
__device__ __forceinline__ float fexp2(float x) { return __builtin_amdgcn_exp2f(x); }
#else
__device__ __forceinline__ float fexp2(float x) { return exp2f(x); }
#endif

#define MFMA16(a, b, c) __builtin_amdgcn_mfma_f32_16x16x32_bf16((a), (b), (c), 0, 0, 0)
#define MFMA32(a, b, c) __builtin_amdgcn_mfma_f32_32x32x16_bf16((a), (b), (c), 0, 0, 0)

// ---------------- kernel 1: fp32 -> bf16 cast (hidden states) ----------------
__global__ __launch_bounds__(256) void k_cast(const float4* __restrict__ in,
                                              us4* __restrict__ o, int n4) {
  int i = blockIdx.x * 256 + threadIdx.x;
  if (i >= n4) return;
  float4 v = in[i];
  us4 r;
  r.x = f2bf(v.x); r.y = f2bf(v.y); r.z = f2bf(v.z); r.w = f2bf(v.w);
  o[i] = r;
}

// ------------- kernel 2: transpose-cast W (KxN fp32) -> WT (NxK bf16) -------------
__global__ __launch_bounds__(256) void k_transW(const float* __restrict__ W0,
    const float* __restrict__ W1, const float* __restrict__ W2,
    unsigned short* __restrict__ T0, unsigned short* __restrict__ T1,
    unsigned short* __restrict__ T2) {
  int z = blockIdx.z;
  const float* W = (z == 0) ? W0 : (z == 1) ? W1 : W2;
  unsigned short* T = (z == 0) ? T0 : (z == 1) ? T1 : T2;
  int kb = blockIdx.y * 64;
  int nb = blockIdx.x * 64;
  __shared__ float tile[64 * 64];
  int t = threadIdx.x;
#pragma unroll
  for (int p = 0; p < 4; ++p) {
    int cid = p * 256 + t;
    int row = cid >> 4, c4 = cid & 15;
    int slot = (c4 + (row >> 3)) & 15;
    float4 v = *(const float4*)&W[(size_t)(kb + row) * DIM + nb + c4 * 4];
    *(float4*)&tile[row * 64 + slot * 4] = v;
  }
  __syncthreads();
#pragma unroll
  for (int p = 0; p < 2; ++p) {
    int cid = p * 256 + t;
    int nl = cid >> 3, c8 = cid & 7;
    us8 o;
#pragma unroll
    for (int j = 0; j < 8; ++j) {
      int k = c8 * 8 + j;
      int slot = ((nl >> 2) + (k >> 3)) & 15;
      o[j] = f2bf(tile[k * 64 + slot * 4 + (nl & 3)]);
    }
    *(us8*)&T[(size_t)(nb + nl) * DIM + kb + c8 * 8] = o;
  }
}

// ------------- kernel 3: GEMM 128x128 (R13 structure) + fused RMSNorm/RoPE ----
// Each block's n-range = one head (nb>>7); m-range = 128 full s-rows -> block
// owns complete RMS reduction rows. z=0(q)/1(k): bias+RMS+RoPE fused epilogue
// (q scaled by log2e/sqrt(128) for exp2-domain attn); z=2(v): bias only.
__global__ __launch_bounds__(256, 3) void k_gemm(const unsigned short* __restrict__ A,
    const unsigned short* __restrict__ B0, const unsigned short* __restrict__ B1,
    const unsigned short* __restrict__ B2, const float* __restrict__ c0,
    const float* __restrict__ c1, const float* __restrict__ c2,
    const float* __restrict__ cosT, const float* __restrict__ sinT,
    const float* __restrict__ gq, const float* __restrict__ gk,
    unsigned short* __restrict__ o0, unsigned short* __restrict__ o1,
    unsigned short* __restrict__ o2) {
  const int b = blockIdx.x;
  const int yb = b % 32;
  const int r2b = b / 32;
  const int xb = r2b % 24;
  const int z = r2b / 24;
  const unsigned short* Bt = (z == 0) ? B0 : (z == 1) ? B1 : B2;
  const float* bias = (z == 0) ? c0 : (z == 1) ? c1 : c2;
  unsigned short* outp = (z == 0) ? o0 : (z == 1) ? o1 : o2;
  const int nb = xb * 128;
  const int mb = yb * 128;
  const int t = threadIdx.x;
  const int w = t >> 6, l = t & 63;
  const int wr = w >> 1, wc = w & 1;
  const int lq = l & 15, lg = l >> 4;
  __shared__ unsigned short lA[128 * 64];
  __shared__ unsigned short lB[128 * 64];
  __shared__ float lds_sq[128 * 2];
  f32x4 acc[4][4];
#pragma unroll
  for (int i = 0; i < 4; ++i)
#pragma unroll
    for (int j = 0; j < 4; ++j) acc[i][j] = (f32x4){0.f, 0.f, 0.f, 0.f};

  for (int kb = 0; kb < DIM; kb += 64) {
    __syncthreads();
#pragma unroll
    for (int r = 0; r < 4; ++r) {
      int row = (w * 4 + r) * 8 + (l >> 3);
      int sl = (l & 7) ^ (row & 7);
      async16(&lA[(w * 4 + r) * 512], A + (size_t)(mb + row) * DIM + kb + sl * 8);
      async16(&lB[(w * 4 + r) * 512], Bt + (size_t)(nb + row) * DIM + kb + sl * 8);
    }
    __syncthreads();
#pragma unroll
    for (int kc = 0; kc < 2; ++kc) {
      bfv8 af[4], bfv[4];
#pragma unroll
      for (int mf = 0; mf < 4; ++mf) {
        int row = wr * 64 + mf * 16 + lq;
        af[mf] = *(const bfv8*)&lA[row * 64 + (((kc * 4 + lg) ^ (row & 7)) * 8)];
      }
#pragma unroll
      for (int nf = 0; nf < 4; ++nf) {
        int row = wc * 64 + nf * 16 + lq;
        bfv[nf] = *(const bfv8*)&lB[row * 64 + (((kc * 4 + lg) ^ (row & 7)) * 8)];
      }
#pragma unroll
      for (int mf = 0; mf < 4; ++mf)
#pragma unroll
        for (int nf = 0; nf < 4; ++nf)
          acc[mf][nf] = MFMA16(af[mf], bfv[nf], acc[mf][nf]);
    }
  }

  // ---- bias add (fp32) ----
  float bv4[4];
#pragma unroll
  for (int nf = 0; nf < 4; ++nf) bv4[nf] = bias[nb + wc * 64 + nf * 16 + lq];
#pragma unroll
  for (int mf = 0; mf < 4; ++mf)
#pragma unroll
    for (int nf = 0; nf < 4; ++nf)
#pragma unroll
      for (int r = 0; r < 4; ++r) acc[mf][nf][r] += bv4[nf];

  const int hh = nb >> 7;  // one head per block
  unsigned short* obase0 = outp + (size_t)hh * SEQ * HD;

  if (z == 2) {  // V: plain write (block-uniform branch)
#pragma unroll
    for (int nf = 0; nf < 4; ++nf) {
      int dd = wc * 64 + nf * 16 + lq;
#pragma unroll
      for (int mf = 0; mf < 4; ++mf) {
        int srow = mb + wr * 64 + mf * 16 + lg * 4;
#pragma unroll
        for (int r = 0; r < 4; ++r)
          obase0[(size_t)(srow + r) * HD + dd] = f2bf(acc[mf][nf][r]);
      }
    }
    return;
  }

  // ---- fused RMSNorm: per-row sum of squares ----
  // lanes with equal lg hold the same rows (row = wr*64+mf*16+lg*4+r), the 16
  // lq lanes hold different cols -> shfl_xor 1/2/4/8 reduces this wave's 64 cols.
  float psum[4][4];
#pragma unroll
  for (int mf = 0; mf < 4; ++mf)
#pragma unroll
    for (int r = 0; r < 4; ++r) {
      float p = acc[mf][0][r] * acc[mf][0][r];
      p += acc[mf][1][r] * acc[mf][1][r];
      p += acc[mf][2][r] * acc[mf][2][r];
      p += acc[mf][3][r] * acc[mf][3][r];
      p += __shfl_xor(p, 1);
      p += __shfl_xor(p, 2);
      p += __shfl_xor(p, 4);
      p += __shfl_xor(p, 8);
      psum[mf][r] = p;
    }
  if (lq == 0) {
#pragma unroll
    for (int mf = 0; mf < 4; ++mf)
#pragma unroll
      for (int r = 0; r < 4; ++r)
        lds_sq[(wr * 64 + mf * 16 + lg * 4 + r) * 2 + wc] = psum[mf][r];
  }
  __syncthreads();

  const float* g = (z == 0) ? gq : gk;
  float gvec[4];
#pragma unroll
  for (int nf = 0; nf < 4; ++nf) gvec[nf] = g[wc * 64 + nf * 16 + lq];
  const float qs = (z == 0) ? 0.1275174373f : 1.0f;  // log2(e)/sqrt(128) for q

#pragma unroll
  for (int mf = 0; mf < 4; ++mf)
#pragma unroll
    for (int r = 0; r < 4; ++r) {
      int row = wr * 64 + mf * 16 + lg * 4 + r;
      float tot = lds_sq[row * 2] + lds_sq[row * 2 + 1];
      float rrv = rsqrtf(tot * (1.0f / 128.0f) + 1e-6f);
      int s = mb + row;
#pragma unroll
      for (int nf = 0; nf < 4; ++nf) {
        int dd = wc * 64 + nf * 16 + lq;
        float y = acc[mf][nf][r] * rrv * gvec[nf];
        float yp = __shfl_xor(y, 1);  // RoPE partner: adjacent lq lane, same row
        float cc = cosT[s * HD + dd], sn = sinT[s * HD + dd];
        float o = (lq & 1) ? fmaf(yp, sn, y * cc) : fmaf(-yp, sn, y * cc);
        obase0[(size_t)s * HD + dd] = f2bf(o * qs);
      }
    }
}

// ------------- kernel 5: V transpose  v[h][s][d] -> vt[h][d][s] -------------
__global__ __launch_bounds__(256) void k_transV(const unsigned short* __restrict__ vb,
                                                unsigned short* __restrict__ vt) {
  int hh = blockIdx.y;
  int sb = blockIdx.x * 64;
  __shared__ unsigned short tile[64 * 128];
  int t = threadIdx.x;
#pragma unroll
  for (int p = 0; p < 4; ++p) {
    int cid = p * 256 + t;
    int row = cid >> 4, c = cid & 15;
    int slot = (c + (row >> 3)) & 15;
    us8 v = *(const us8*)&vb[((size_t)hh * SEQ + sb + row) * HD + c * 8];
    *(us8*)&tile[row * 128 + slot * 8] = v;
  }
  __syncthreads();
#pragma unroll
  for (int p = 0; p < 4; ++p) {
    int cid = p * 256 + t;
    int d = cid >> 3, c8 = cid & 7;
    us8 o;
#pragma unroll
    for (int j = 0; j < 8; ++j) {
      int s = c8 * 8 + j;
      int slot = ((d >> 3) + (s >> 3)) & 15;
      o[j] = tile[s * 128 + slot * 8 + (d & 7)];
    }
    *(us8*)&vt[((size_t)hh * HD + d) * SEQ + sb + c8 * 8] = o;
  }
}

// ------------- kernel 6: flash attention (R13: head-congruent XCD clustering) -------------
__global__ __launch_bounds__(256, 2) void k_attn(const unsigned short* __restrict__ qg,
    const unsigned short* __restrict__ kg, const unsigned short* __restrict__ vtg,
    float* __restrict__ outp) {
  const int bflat = blockIdx.x;
  const int h = bflat % 24;
  const int qb0 = (bflat / 24) * 128;
  const int t = threadIdx.x;
  const int w = t >> 6, l = t & 63;
  const int l31 = l & 31, hi = l >> 5;

  __shared__ unsigned short lKf[2 * 8192];
  __shared__ unsigned short lVf[2 * 8192];

  bfv8 qf[8];
  {
    const unsigned short* qrow = qg + ((size_t)h * SEQ + qb0 + w * 32 + l31) * HD + hi * 8;
#pragma unroll
    for (int ks = 0; ks < 8; ++ks) qf[ks] = *(const bfv8*)(qrow + ks * 16);
  }

  int kidx[8], vidx[4][2];
#pragma unroll
  for (int ks = 0; ks < 8; ++ks)
    kidx[ks] = l31 * 128 + (((ks * 2 + hi) ^ (l31 & 7) ^ ((l31 >> 3) & 1)) * 8);
#pragma unroll
  for (int dt = 0; dt < 4; ++dt)
#pragma unroll
    for (int ksub = 0; ksub < 2; ++ksub)
      vidx[dt][ksub] =
          (dt * 32 + l31) * 32 + (((ksub * 2 + hi) ^ (l31 & 3) ^ ((l31 >> 2) & 3)) * 8);

  const unsigned short *kp0, *kp1, *vp0, *vp1;
  {
    int kr0 = w * 4 + (l >> 4), kr1 = 16 + kr0;
    kp0 = kg + ((size_t)h * SEQ + kr0) * HD + (((l & 15) ^ (kr0 & 7) ^ ((kr0 >> 3) & 1)) * 8);
    kp1 = kg + ((size_t)h * SEQ + kr1) * HD + (((l & 15) ^ (kr1 & 7) ^ ((kr1 >> 3) & 1)) * 8);
    int vr0 = w * 16 + (l >> 2), vr1 = 64 + vr0;
    vp0 = vtg + ((size_t)h * HD + vr0) * SEQ + (((l & 3) ^ (vr0 & 3) ^ ((vr0 >> 2) & 3)) * 8);
    vp1 = vtg + ((size_t)h * HD + vr1) * SEQ + (((l & 3) ^ (vr1 & 3) ^ ((vr1 >> 2) & 3)) * 8);
  }

#define STAGE(B)                                                              \
  do {                                                                        \
    async16(&lKf[(B) * 8192 + w * 512], kp0);                                 \
    async16(&lKf[(B) * 8192 + 2048 + w * 512], kp1);                          \
    async16(&lKf[(B) * 8192 + 4096 + w * 512], kp0 + 32 * HD);                \
    async16(&lKf[(B) * 8192 + 6144 + w * 512], kp1 + 32 * HD);                \
    async16(&lVf[(B) * 8192 + w * 512], vp0);                                 \
    async16(&lVf[(B) * 8192 + 2048 + w * 512], vp1);                          \
    async16(&lVf[(B) * 8192 + 4096 + w * 512], vp0 + 32);                     \
    async16(&lVf[(B) * 8192 + 6144 + w * 512], vp1 + 32);                     \
    kp0 += 64 * HD; kp1 += 64 * HD; vp0 += 64; vp1 += 64;                     \
  } while (0)

  f32x16 oacc[4];
#pragma unroll
  for (int dt = 0; dt < 4; ++dt)
#pragma unroll
    for (int r = 0; r < 16; ++r) oacc[dt][r] = 0.f;
  float l_run = 0.f;

  STAGE(0);

  auto phase = [&](auto bufc, auto stagec) {
    constexpr int CUR = decltype(bufc)::value;
    constexpr int DOSTAGE = decltype(stagec)::value;
    asm volatile("s_waitcnt vmcnt(0)" ::: "memory");
    __builtin_amdgcn_s_barrier();
    __builtin_amdgcn_sched_barrier(0);
    if constexpr (DOSTAGE) STAGE(CUR ^ 1);
    __builtin_amdgcn_sched_barrier(0);

    f32x16 sa, sb;
#pragma unroll
    for (int r = 0; r < 16; ++r) { sa[r] = 0.f; sb[r] = 0.f; }
    __builtin_amdgcn_s_setprio(1);
#pragma unroll
    for (int ks = 0; ks < 8; ++ks) {
      bfv8 kfa = *(const bfv8*)&lKf[CUR * 8192 + kidx[ks]];
      bfv8 kfb = *(const bfv8*)&lKf[CUR * 8192 + 4096 + kidx[ks]];
      sa = MFMA32(kfa, qf[ks], sa);
      sb = MFMA32(kfb, qf[ks], sb);
    }
    __builtin_amdgcn_s_setprio(0);

#pragma unroll
    for (int r = 0; r < 16; ++r) { sa[r] = fexp2(sa[r]); sb[r] = fexp2(sb[r]); }
    {
      float a0 = (sa[0] + sa[1]) + (sa[2] + sa[3]);
      float a1 = (sa[4] + sa[5]) + (sa[6] + sa[7]);
      float a2 = (sa[8] + sa[9]) + (sa[10] + sa[11]);
      float a3 = (sa[12] + sa[13]) + (sa[14] + sa[15]);
      float b0 = (sb[0] + sb[1]) + (sb[2] + sb[3]);
      float b1 = (sb[4] + sb[5]) + (sb[6] + sb[7]);
      float b2 = (sb[8] + sb[9]) + (sb[10] + sb[11]);
      float b3 = (sb[12] + sb[13]) + (sb[14] + sb[15]);
      l_run += ((a0 + a1) + (a2 + a3)) + ((b0 + b1) + (b2 + b3));
    }

    bfv8 paA[2], paB[2];
    {
      unsigned int a0 = cvtpk(sa[0], sa[1]), a1 = cvtpk(sa[2], sa[3]);
      unsigned int b0 = cvtpk(sa[4], sa[5]), b1 = cvtpk(sa[6], sa[7]);
      unsigned int c0 = cvtpk(sa[8], sa[9]), c1 = cvtpk(sa[10], sa[11]);
      unsigned int d0 = cvtpk(sa[12], sa[13]), d1 = cvtpk(sa[14], sa[15]);
      pl32swap(a0, b0); pl32swap(a1, b1); pl32swap(c0, d0); pl32swap(c1, d1);
      paA[0] = __builtin_bit_cast(bfv8, make_uint4(a0, a1, b0, b1));
      paA[1] = __builtin_bit_cast(bfv8, make_uint4(c0, c1, d0, d1));
      a0 = cvtpk(sb[0], sb[1]); a1 = cvtpk(sb[2], sb[3]);
      b0 = cvtpk(sb[4], sb[5]); b1 = cvtpk(sb[6], sb[7]);
      c0 = cvtpk(sb[8], sb[9]); c1 = cvtpk(sb[10], sb[11]);
      d0 = cvtpk(sb[12], sb[13]); d1 = cvtpk(sb[14], sb[15]);
      pl32swap(a0, b0); pl32swap(a1, b1); pl32swap(c0, d0); pl32swap(c1, d1);
      paB[0] = __builtin_bit_cast(bfv8, make_uint4(a0, a1, b0, b1));
      paB[1] = __builtin_bit_cast(bfv8, make_uint4(c0, c1, d0, d1));
    }

    __builtin_amdgcn_s_setprio(1);
#pragma unroll
    for (int dt = 0; dt < 4; ++dt) {
#pragma unroll
      for (int ksub = 0; ksub < 2; ++ksub) {
        bfv8 vfa = *(const bfv8*)&lVf[CUR * 8192 + vidx[dt][ksub]];
        oacc[dt] = MFMA32(paA[ksub], vfa, oacc[dt]);
      }
#pragma unroll
      for (int ksub = 0; ksub < 2; ++ksub) {
        bfv8 vfb = *(const bfv8*)&lVf[CUR * 8192 + 4096 + vidx[dt][ksub]];
        oacc[dt] = MFMA32(paB[ksub], vfb, oacc[dt]);
      }
    }
    __builtin_amdgcn_s_setprio(0);
  };

  for (int it = 0; it < 31; ++it) {
    phase(ic<0>{}, ic<1>{});
    phase(ic<1>{}, ic<1>{});
  }
  phase(ic<0>{}, ic<1>{});
  phase(ic<1>{}, ic<0>{});

  l_run += __shfl_xor(l_run, 32);
  float linv = 1.0f / l_run;
#pragma unroll
  for (int r = 0; r < 16; ++r) {
    int qr = (r & 3) + 8 * (r >> 2) + 4 * hi;
    float lr = __shfl(linv, qr);
    float* orow = outp + (size_t)(qb0 + w * 32 + qr) * DIM + h * HD;
#pragma unroll
    for (int dt = 0; dt < 4; ++dt) orow[dt * 32 + l31] = oacc[dt][r] * lr;
  }
#undef STAGE
}

extern "C" void kernel_launch(void* const* d_in, const int* in_sizes, int n_in,
                              void* d_out, int out_size, void* d_ws, size_t ws_size,
                              hipStream_t stream) {
  const float* hs = (const float*)d_in[0];
  const float* cosT = (const float*)d_in[1];
  const float* sinT = (const float*)d_in[2];
  const float* Wq = (const float*)d_in[3];
  const float* bq = (const float*)d_in[4];
  const float* Wk = (const float*)d_in[5];
  const float* bk = (const float*)d_in[6];
  const float* Wv = (const float*)d_in[7];
  const float* bv = (const float*)d_in[8];
  const float* gq = (const float*)d_in[9];
  const float* gk = (const float*)d_in[10];
  float* out = (float*)d_out;

  char* ws = (char*)d_ws;
  const size_t SZ_HS = (size_t)SEQ * DIM * 2;
  const size_t SZ_W = (size_t)DIM * DIM * 2;
  const size_t SZ_HEAD = (size_t)NH * SEQ * HD * 2;
  unsigned short* hsb = (unsigned short*)ws;               ws += SZ_HS;
  unsigned short* WqT = (unsigned short*)ws;               ws += SZ_W;
  unsigned short* WkT = (unsigned short*)ws;               ws += SZ_W;
  unsigned short* WvT = (unsigned short*)ws;               ws += SZ_W;
  unsigned short* q_b = (unsigned short*)ws;               ws += SZ_HEAD;
  unsigned short* k_b = (unsigned short*)ws;               ws += SZ_HEAD;
  unsigned short* v_b = (unsigned short*)ws;               ws += SZ_HEAD;
  unsigned short* vtr = (unsigned short*)ws;               ws += SZ_HEAD;

  int n4 = SEQ * DIM / 4;
  k_cast<<<dim3(n4 / 256), dim3(256), 0, stream>>>((const float4*)hs, (us4*)hsb, n4);
  k_transW<<<dim3(48, 48, 3), dim3(256), 0, stream>>>(Wq, Wk, Wv, WqT, WkT, WvT);
  k_gemm<<<dim3(2304), dim3(256), 0, stream>>>(hsb, WqT, WkT, WvT, bq, bk, bv,
                                               cosT, sinT, gq, gk, q_b, k_b, v_b);
  k_transV<<<dim3(64, 24), dim3(256), 0, stream>>>(v_b, vtr);
  k_attn<<<dim3(768), dim3(256), 0, stream>>>(q_b, k_b, vtr, out);
}

// Round 17
// 510.220 us; speedup vs baseline: 1.1783x; 1.0137x over previous
//
#include <hip/hip_runtime.h>
#include <hip/hip_bf16.h>
#include <stdint.h>

#define DIM 3072
#define SEQ 4096
#define NH 24
#define HD 128

typedef __hip_bfloat16 bf16;
typedef __bf16 bfv8 __attribute__((ext_vector_type(8)));
typedef float f32x4 __attribute__((ext_vector_type(4)));
typedef float f32x16 __attribute__((ext_vector_type(16)));
typedef unsigned short us4 __attribute__((ext_vector_type(4)));
typedef unsigned short us8 __attribute__((ext_vector_type(8)));

template <int N> struct ic { static constexpr int value = N; };

__device__ __forceinline__ void async16(void* lds, const void* g) {
  __builtin_amdgcn_global_load_lds((const __attribute__((address_space(1))) void*)g,
                                   (__attribute__((address_space(3))) void*)lds, 16, 0, 0);
}

__device__ __forceinline__ unsigned short f2bf(float f) {
  unsigned int u = __builtin_bit_cast(unsigned int, f);
  u += 0x7fffu + ((u >> 16) & 1u);
  return (unsigned short)(u >> 16);
}
__device__ __forceinline__ float bf2f(unsigned short b) {
  return __builtin_bit_cast(float, (unsigned int)b << 16);
}
__device__ __forceinline__ unsigned int cvtpk(float lo, float hi) {
  unsigned int r;
  asm("v_cvt_pk_bf16_f32 %0, %1, %2" : "=v"(r) : "v"(lo), "v"(hi));
  return r;
}
__device__ __forceinline__ void pl32swap(unsigned int& a, unsigned int& b) {
  asm volatile("v_permlane32_swap_b32 %0, %1" : "+v"(a), "+v"(b));
}
#if __has_builtin(__builtin_amdgcn_exp2f)
__device__ __forceinline__ float fexp2(float x) { return __builtin_amdgcn_exp2f(x); }
#else
__device__ __forceinline__ float fexp2(float x) { return exp2f(x); }
#endif

#define MFMA16(a, b, c) __builtin_amdgcn_mfma_f32_16x16x32_bf16((a), (b), (c), 0, 0, 0)
#define MFMA32(a, b, c) __builtin_amdgcn_mfma_f32_32x32x16_bf16((a), (b), (c), 0, 0, 0)

// ------ kernel 1: merged prep. z<3: transpose-cast W -> WT bf16; z==3: cast hs -> bf16 ------
__global__ __launch_bounds__(256) void k_prep(const float* __restrict__ hs,
    us4* __restrict__ hsb, const float* __restrict__ W0, const float* __restrict__ W1,
    const float* __restrict__ W2, unsigned short* __restrict__ T0,
    unsigned short* __restrict__ T1, unsigned short* __restrict__ T2) {
  int z = blockIdx.z;
  int t = threadIdx.x;
  if (z == 3) {
    // grid-stride cast of hs (fp32 -> bf16), n4 = SEQ*DIM/4 float4 chunks
    const int n4 = SEQ * DIM / 4;
    const int stride = 48 * 48 * 256;
    const float4* in = (const float4*)hs;
    for (int i = (blockIdx.y * 48 + blockIdx.x) * 256 + t; i < n4; i += stride) {
      float4 v = in[i];
      us4 r;
      r.x = f2bf(v.x); r.y = f2bf(v.y); r.z = f2bf(v.z); r.w = f2bf(v.w);
      hsb[i] = r;
    }
    return;
  }
  const float* W = (z == 0) ? W0 : (z == 1) ? W1 : W2;
  unsigned short* T = (z == 0) ? T0 : (z == 1) ? T1 : T2;
  int kb = blockIdx.y * 64;
  int nb = blockIdx.x * 64;
  __shared__ float tile[64 * 64];
#pragma unroll
  for (int p = 0; p < 4; ++p) {
    int cid = p * 256 + t;
    int row = cid >> 4, c4 = cid & 15;
    int slot = (c4 + (row >> 3)) & 15;
    float4 v = *(const float4*)&W[(size_t)(kb + row) * DIM + nb + c4 * 4];
    *(float4*)&tile[row * 64 + slot * 4] = v;
  }
  __syncthreads();
#pragma unroll
  for (int p = 0; p < 2; ++p) {
    int cid = p * 256 + t;
    int nl = cid >> 3, c8 = cid & 7;
    us8 o;
#pragma unroll
    for (int j = 0; j < 8; ++j) {
      int k = c8 * 8 + j;
      int slot = ((nl >> 2) + (k >> 3)) & 15;
      o[j] = f2bf(tile[k * 64 + slot * 4 + (nl & 3)]);
    }
    *(us8*)&T[(size_t)(nb + nl) * DIM + kb + c8 * 8] = o;
  }
}

// ------------- kernel 2: GEMM 128x128 + fused RMSNorm/RoPE (q,k) / V^T scatter (v) ----
// z=0(q)/1(k): bias+RMS+RoPE fused epilogue (q scaled log2e/sqrt(128));
// z=2(v): bias, then write V^T DIRECTLY to vt[h][d][s] (packed 8B stores; each
// (d, s-block) L2 line fully covered by the block) -> k_transV deleted.
__global__ __launch_bounds__(256, 3) void k_gemm(const unsigned short* __restrict__ A,
    const unsigned short* __restrict__ B0, const unsigned short* __restrict__ B1,
    const unsigned short* __restrict__ B2, const float* __restrict__ c0,
    const float* __restrict__ c1, const float* __restrict__ c2,
    const float* __restrict__ cosT, const float* __restrict__ sinT,
    const float* __restrict__ gq, const float* __restrict__ gk,
    unsigned short* __restrict__ o0, unsigned short* __restrict__ o1,
    unsigned short* __restrict__ o2) {
  const int b = blockIdx.x;
  const int yb = b % 32;
  const int r2b = b / 32;
  const int xb = r2b % 24;
  const int z = r2b / 24;
  const unsigned short* Bt = (z == 0) ? B0 : (z == 1) ? B1 : B2;
  const float* bias = (z == 0) ? c0 : (z == 1) ? c1 : c2;
  unsigned short* outp = (z == 0) ? o0 : (z == 1) ? o1 : o2;
  const int nb = xb * 128;
  const int mb = yb * 128;
  const int t = threadIdx.x;
  const int w = t >> 6, l = t & 63;
  const int wr = w >> 1, wc = w & 1;
  const int lq = l & 15, lg = l >> 4;
  __shared__ unsigned short lA[128 * 64];
  __shared__ unsigned short lB[128 * 64];
  __shared__ float lds_sq[128 * 2];
  f32x4 acc[4][4];
#pragma unroll
  for (int i = 0; i < 4; ++i)
#pragma unroll
    for (int j = 0; j < 4; ++j) acc[i][j] = (f32x4){0.f, 0.f, 0.f, 0.f};

  for (int kb = 0; kb < DIM; kb += 64) {
    __syncthreads();
#pragma unroll
    for (int r = 0; r < 4; ++r) {
      int row = (w * 4 + r) * 8 + (l >> 3);
      int sl = (l & 7) ^ (row & 7);
      async16(&lA[(w * 4 + r) * 512], A + (size_t)(mb + row) * DIM + kb + sl * 8);
      async16(&lB[(w * 4 + r) * 512], Bt + (size_t)(nb + row) * DIM + kb + sl * 8);
    }
    __syncthreads();
#pragma unroll
    for (int kc = 0; kc < 2; ++kc) {
      bfv8 af[4], bfv[4];
#pragma unroll
      for (int mf = 0; mf < 4; ++mf) {
        int row = wr * 64 + mf * 16 + lq;
        af[mf] = *(const bfv8*)&lA[row * 64 + (((kc * 4 + lg) ^ (row & 7)) * 8)];
      }
#pragma unroll
      for (int nf = 0; nf < 4; ++nf) {
        int row = wc * 64 + nf * 16 + lq;
        bfv[nf] = *(const bfv8*)&lB[row * 64 + (((kc * 4 + lg) ^ (row & 7)) * 8)];
      }
#pragma unroll
      for (int mf = 0; mf < 4; ++mf)
#pragma unroll
        for (int nf = 0; nf < 4; ++nf)
          acc[mf][nf] = MFMA16(af[mf], bfv[nf], acc[mf][nf]);
    }
  }

  // ---- bias add (fp32) ----
  float bv4[4];
#pragma unroll
  for (int nf = 0; nf < 4; ++nf) bv4[nf] = bias[nb + wc * 64 + nf * 16 + lq];
#pragma unroll
  for (int mf = 0; mf < 4; ++mf)
#pragma unroll
    for (int nf = 0; nf < 4; ++nf)
#pragma unroll
      for (int r = 0; r < 4; ++r) acc[mf][nf][r] += bv4[nf];

  const int hh = nb >> 7;  // one head per block

  if (z == 2) {  // V: write V^T directly (vt[h][d][s]); 8B packed stores
    unsigned short* vbase = outp + (size_t)hh * HD * SEQ;
#pragma unroll
    for (int nf = 0; nf < 4; ++nf) {
      int dd = wc * 64 + nf * 16 + lq;
#pragma unroll
      for (int mf = 0; mf < 4; ++mf) {
        int s0 = mb + wr * 64 + mf * 16 + lg * 4;
        us4 pk;
#pragma unroll
        for (int r = 0; r < 4; ++r) pk[r] = f2bf(acc[mf][nf][r]);
        *(us4*)&vbase[(size_t)dd * SEQ + s0] = pk;
      }
    }
    return;
  }

  unsigned short* obase0 = outp + (size_t)hh * SEQ * HD;

  // ---- fused RMSNorm: per-row sum of squares ----
  float psum[4][4];
#pragma unroll
  for (int mf = 0; mf < 4; ++mf)
#pragma unroll
    for (int r = 0; r < 4; ++r) {
      float p = acc[mf][0][r] * acc[mf][0][r];
      p += acc[mf][1][r] * acc[mf][1][r];
      p += acc[mf][2][r] * acc[mf][2][r];
      p += acc[mf][3][r] * acc[mf][3][r];
      p += __shfl_xor(p, 1);
      p += __shfl_xor(p, 2);
      p += __shfl_xor(p, 4);
      p += __shfl_xor(p, 8);
      psum[mf][r] = p;
    }
  if (lq == 0) {
#pragma unroll
    for (int mf = 0; mf < 4; ++mf)
#pragma unroll
      for (int r = 0; r < 4; ++r)
        lds_sq[(wr * 64 + mf * 16 + lg * 4 + r) * 2 + wc] = psum[mf][r];
  }
  __syncthreads();

  const float* g = (z == 0) ? gq : gk;
  float gvec[4];
#pragma unroll
  for (int nf = 0; nf < 4; ++nf) gvec[nf] = g[wc * 64 + nf * 16 + lq];
  const float qs = (z == 0) ? 0.1275174373f : 1.0f;  // log2(e)/sqrt(128) for q

#pragma unroll
  for (int mf = 0; mf < 4; ++mf)
#pragma unroll
    for (int r = 0; r < 4; ++r) {
      int row = wr * 64 + mf * 16 + lg * 4 + r;
      float tot = lds_sq[row * 2] + lds_sq[row * 2 + 1];
      float rrv = rsqrtf(tot * (1.0f / 128.0f) + 1e-6f);
      int s = mb + row;
#pragma unroll
      for (int nf = 0; nf < 4; ++nf) {
        int dd = wc * 64 + nf * 16 + lq;
        float y = acc[mf][nf][r] * rrv * gvec[nf];
        float yp = __shfl_xor(y, 1);  // RoPE partner: adjacent lq lane, same row
        float cc = cosT[s * HD + dd], sn = sinT[s * HD + dd];
        float o = (lq & 1) ? fmaf(yp, sn, y * cc) : fmaf(-yp, sn, y * cc);
        obase0[(size_t)s * HD + dd] = f2bf(o * qs);
      }
    }
}

// ------------- kernel 3: flash attention (R13: head-congruent XCD clustering) -------------
__global__ __launch_bounds__(256, 2) void k_attn(const unsigned short* __restrict__ qg,
    const unsigned short* __restrict__ kg, const unsigned short* __restrict__ vtg,
    float* __restrict__ outp) {
  const int bflat = blockIdx.x;
  const int h = bflat % 24;
  const int qb0 = (bflat / 24) * 128;
  const int t = threadIdx.x;
  const int w = t >> 6, l = t & 63;
  const int l31 = l & 31, hi = l >> 5;

  __shared__ unsigned short lKf[2 * 8192];
  __shared__ unsigned short lVf[2 * 8192];

  bfv8 qf[8];
  {
    const unsigned short* qrow = qg + ((size_t)h * SEQ + qb0 + w * 32 + l31) * HD + hi * 8;
#pragma unroll
    for (int ks = 0; ks < 8; ++ks) qf[ks] = *(const bfv8*)(qrow + ks * 16);
  }

  int kidx[8], vidx[4][2];
#pragma unroll
  for (int ks = 0; ks < 8; ++ks)
    kidx[ks] = l31 * 128 + (((ks * 2 + hi) ^ (l31 & 7) ^ ((l31 >> 3) & 1)) * 8);
#pragma unroll
  for (int dt = 0; dt < 4; ++dt)
#pragma unroll
    for (int ksub = 0; ksub < 2; ++ksub)
      vidx[dt][ksub] =
          (dt * 32 + l31) * 32 + (((ksub * 2 + hi) ^ (l31 & 3) ^ ((l31 >> 2) & 3)) * 8);

  const unsigned short *kp0, *kp1, *vp0, *vp1;
  {
    int kr0 = w * 4 + (l >> 4), kr1 = 16 + kr0;
    kp0 = kg + ((size_t)h * SEQ + kr0) * HD + (((l & 15) ^ (kr0 & 7) ^ ((kr0 >> 3) & 1)) * 8);
    kp1 = kg + ((size_t)h * SEQ + kr1) * HD + (((l & 15) ^ (kr1 & 7) ^ ((kr1 >> 3) & 1)) * 8);
    int vr0 = w * 16 + (l >> 2), vr1 = 64 + vr0;
    vp0 = vtg + ((size_t)h * HD + vr0) * SEQ + (((l & 3) ^ (vr0 & 3) ^ ((vr0 >> 2) & 3)) * 8);
    vp1 = vtg + ((size_t)h * HD + vr1) * SEQ + (((l & 3) ^ (vr1 & 3) ^ ((vr1 >> 2) & 3)) * 8);
  }

#define STAGE(B)                                                              \
  do {                                                                        \
    async16(&lKf[(B) * 8192 + w * 512], kp0);                                 \
    async16(&lKf[(B) * 8192 + 2048 + w * 512], kp1);                          \
    async16(&lKf[(B) * 8192 + 4096 + w * 512], kp0 + 32 * HD);                \
    async16(&lKf[(B) * 8192 + 6144 + w * 512], kp1 + 32 * HD);                \
    async16(&lVf[(B) * 8192 + w * 512], vp0);                                 \
    async16(&lVf[(B) * 8192 + 2048 + w * 512], vp1);                          \
    async16(&lVf[(B) * 8192 + 4096 + w * 512], vp0 + 32);                     \
    async16(&lVf[(B) * 8192 + 6144 + w * 512], vp1 + 32);                     \
    kp0 += 64 * HD; kp1 += 64 * HD; vp0 += 64; vp1 += 64;                     \
  } while (0)

  f32x16 oacc[4];
#pragma unroll
  for (int dt = 0; dt < 4; ++dt)
#pragma unroll
    for (int r = 0; r < 16; ++r) oacc[dt][r] = 0.f;
  float l_run = 0.f;

  STAGE(0);

  auto phase = [&](auto bufc, auto stagec) {
    constexpr int CUR = decltype(bufc)::value;
    constexpr int DOSTAGE = decltype(stagec)::value;
    asm volatile("s_waitcnt vmcnt(0)" ::: "memory");
    __builtin_amdgcn_s_barrier();
    __builtin_amdgcn_sched_barrier(0);
    if constexpr (DOSTAGE) STAGE(CUR ^ 1);
    __builtin_amdgcn_sched_barrier(0);

    f32x16 sa, sb;
#pragma unroll
    for (int r = 0; r < 16; ++r) { sa[r] = 0.f; sb[r] = 0.f; }
    __builtin_amdgcn_s_setprio(1);
#pragma unroll
    for (int ks = 0; ks < 8; ++ks) {
      bfv8 kfa = *(const bfv8*)&lKf[CUR * 8192 + kidx[ks]];
      bfv8 kfb = *(const bfv8*)&lKf[CUR * 8192 + 4096 + kidx[ks]];
      sa = MFMA32(kfa, qf[ks], sa);
      sb = MFMA32(kfb, qf[ks], sb);
    }
    __builtin_amdgcn_s_setprio(0);

#pragma unroll
    for (int r = 0; r < 16; ++r) { sa[r] = fexp2(sa[r]); sb[r] = fexp2(sb[r]); }
    {
      float a0 = (sa[0] + sa[1]) + (sa[2] + sa[3]);
      float a1 = (sa[4] + sa[5]) + (sa[6] + sa[7]);
      float a2 = (sa[8] + sa[9]) + (sa[10] + sa[11]);
      float a3 = (sa[12] + sa[13]) + (sa[14] + sa[15]);
      float b0 = (sb[0] + sb[1]) + (sb[2] + sb[3]);
      float b1 = (sb[4] + sb[5]) + (sb[6] + sb[7]);
      float b2 = (sb[8] + sb[9]) + (sb[10] + sb[11]);
      float b3 = (sb[12] + sb[13]) + (sb[14] + sb[15]);
      l_run += ((a0 + a1) + (a2 + a3)) + ((b0 + b1) + (b2 + b3));
    }

    bfv8 paA[2], paB[2];
    {
      unsigned int a0 = cvtpk(sa[0], sa[1]), a1 = cvtpk(sa[2], sa[3]);
      unsigned int b0 = cvtpk(sa[4], sa[5]), b1 = cvtpk(sa[6], sa[7]);
      unsigned int c0 = cvtpk(sa[8], sa[9]), c1 = cvtpk(sa[10], sa[11]);
      unsigned int d0 = cvtpk(sa[12], sa[13]), d1 = cvtpk(sa[14], sa[15]);
      pl32swap(a0, b0); pl32swap(a1, b1); pl32swap(c0, d0); pl32swap(c1, d1);
      paA[0] = __builtin_bit_cast(bfv8, make_uint4(a0, a1, b0, b1));
      paA[1] = __builtin_bit_cast(bfv8, make_uint4(c0, c1, d0, d1));
      a0 = cvtpk(sb[0], sb[1]); a1 = cvtpk(sb[2], sb[3]);
      b0 = cvtpk(sb[4], sb[5]); b1 = cvtpk(sb[6], sb[7]);
      c0 = cvtpk(sb[8], sb[9]); c1 = cvtpk(sb[10], sb[11]);
      d0 = cvtpk(sb[12], sb[13]); d1 = cvtpk(sb[14], sb[15]);
      pl32swap(a0, b0); pl32swap(a1, b1); pl32swap(c0, d0); pl32swap(c1, d1);
      paB[0] = __builtin_bit_cast(bfv8, make_uint4(a0, a1, b0, b1));
      paB[1] = __builtin_bit_cast(bfv8, make_uint4(c0, c1, d0, d1));
    }

    __builtin_amdgcn_s_setprio(1);
#pragma unroll
    for (int dt = 0; dt < 4; ++dt) {
#pragma unroll
      for (int ksub = 0; ksub < 2; ++ksub) {
        bfv8 vfa = *(const bfv8*)&lVf[CUR * 8192 + vidx[dt][ksub]];
        oacc[dt] = MFMA32(paA[ksub], vfa, oacc[dt]);
      }
#pragma unroll
      for (int ksub = 0; ksub < 2; ++ksub) {
        bfv8 vfb = *(const bfv8*)&lVf[CUR * 8192 + 4096 + vidx[dt][ksub]];
        oacc[dt] = MFMA32(paB[ksub], vfb, oacc[dt]);
      }
    }
    __builtin_amdgcn_s_setprio(0);
  };

  for (int it = 0; it < 31; ++it) {
    phase(ic<0>{}, ic<1>{});
    phase(ic<1>{}, ic<1>{});
  }
  phase(ic<0>{}, ic<1>{});
  phase(ic<1>{}, ic<0>{});

  l_run += __shfl_xor(l_run, 32);
  float linv = 1.0f / l_run;
#pragma unroll
  for (int r = 0; r < 16; ++r) {
    int qr = (r & 3) + 8 * (r >> 2) + 4 * hi;
    float lr = __shfl(linv, qr);
    float* orow = outp + (size_t)(qb0 + w * 32 + qr) * DIM + h * HD;
#pragma unroll
    for (int dt = 0; dt < 4; ++dt) orow[dt * 32 + l31] = oacc[dt][r] * lr;
  }
#undef STAGE
}

extern "C" void kernel_launch(void* const* d_in, const int* in_sizes, int n_in,
                              void* d_out, int out_size, void* d_ws, size_t ws_size,
                              hipStream_t stream) {
  const float* hs = (const float*)d_in[0];
  const float* cosT = (const float*)d_in[1];
  const float* sinT = (const float*)d_in[2];
  const float* Wq = (const float*)d_in[3];
  const float* bq = (const float*)d_in[4];
  const float* Wk = (const float*)d_in[5];
  const float* bk = (const float*)d_in[6];
  const float* Wv = (const float*)d_in[7];
  const float* bv = (const float*)d_in[8];
  const float* gq = (const float*)d_in[9];
  const float* gk = (const float*)d_in[10];
  float* out = (float*)d_out;

  char* ws = (char*)d_ws;
  const size_t SZ_HS = (size_t)SEQ * DIM * 2;
  const size_t SZ_W = (size_t)DIM * DIM * 2;
  const size_t SZ_HEAD = (size_t)NH * SEQ * HD * 2;
  unsigned short* hsb = (unsigned short*)ws;               ws += SZ_HS;
  unsigned short* WqT = (unsigned short*)ws;               ws += SZ_W;
  unsigned short* WkT = (unsigned short*)ws;               ws += SZ_W;
  unsigned short* WvT = (unsigned short*)ws;               ws += SZ_W;
  unsigned short* q_b = (unsigned short*)ws;               ws += SZ_HEAD;
  unsigned short* k_b = (unsigned short*)ws;               ws += SZ_HEAD;
  unsigned short* vtr = (unsigned short*)ws;               ws += SZ_HEAD;

  k_prep<<<dim3(48, 48, 4), dim3(256), 0, stream>>>(hs, (us4*)hsb, Wq, Wk, Wv,
                                                    WqT, WkT, WvT);
  k_gemm<<<dim3(2304), dim3(256), 0, stream>>>(hsb, WqT, WkT, WvT, bq, bk, bv,
                                               cosT, sinT, gq, gk, q_b, k_b, vtr);
  k_attn<<<dim3(768), dim3(256), 0, stream>>>(q_b, k_b, vtr, out);
}